// Round 7
// baseline (111.751 us; speedup 1.0000x reference)
//
#include <hip/hip_runtime.h>
#include <stdint.h>

#define NI 128
#define NA 285
#define ND 183
#define NT 384
#define RAYS (NA * ND)        // 52155
#define PITCH 133             // dwords per packed row
#define PROWS 132
#define PLDS (PROWS * PITCH + 1)  // 17557 dwords = 70,228 B -> 2 blocks/CU
#define TPB 832               // 13 waves; grid 64 blocks/img
#define WAVES 13
#define SLOTS 832             // wave slots per image (64 blocks x 13)
#define NTASKS (143 * 92)     // 13156 symmetry-group tasks per image
#define TROUNDS 16            // ceil(13156/832)
#define IDXM 17420            // 130*133+130: det-mirror idx' = IDXM - idx
#define BIDXM (IDXM * 4)      // byte-domain mirror constant

typedef __fp16 half2v __attribute__((ext_vector_type(2)));

constexpr float PI_F  = 3.14159265358979323846f;
constexpr float RHO_F = 28.284271247461902f;   // 20*sqrt(2)
constexpr float DX_F  = 0.3125f;
constexpr float DT_F  = 2.0f * RHO_F / NT;

// R20b (compile-fix resubmit: reduce temps renamed t1a/t1b/t2 — `td`
// collided with the chord-bound td at line ~113).
// One ray-group per WAVE, lanes = 64 consecutive t-samples.
// R17-R19 profiles show bank conflicts (25.5K cyc/CU) exceed DS base cost
// (~21K) in every lane layout where one ds_read2 spans multiple rays —
// 64 quasi-random banks. Here each ds_read2 is a SINGLE arithmetic
// progression (per-lane dword stride d = 0.4714*(133*cs +- sn)): banks
// walk d mod 32 -> conflict-free except narrow resonances (~2-4% of
// angles); overlapping addresses near theta=90 broadcast (free).
// Wave = (ap, j) symmetry group; every lane computes its k-sample on all
// 4 mirror rays (inner body verbatim from R19, incl. fmed3 clamp). Chord
// is exact per wave (no envelope max). 13156 tasks/img over 832 slots x
// 16 rounds (stride-832 -> angle-diverse, balanced). Empty chords write 0.
// Reduce: 2-step acc-interleave + 4 butterflies -> lanes 0..3 hold
// acc0..3; tree shapes for acc0/acc2 (and acc1/acc3) differ only by
// commuted adds -> self-pair (ap==142, j==91) double-writes stay fp-equal.
// Column 1 MUST stay zero (pad col 1 = image col -1): mirror reads at
// col' = 130-f1 hit it for in-support boundary samples (R13's bug).
__global__ __launch_bounds__(TPB) void radon_fwd(const float* __restrict__ x,
                                                 float* __restrict__ out) {
    __shared__ __align__(16) unsigned int P[PLDS];
    const int tid = threadIdx.x;
    const int img = blockIdx.x >> 6;
    const int blk = blockIdx.x & 63;

    // Ring-only zero fill (disjoint from pack writes -> single barrier).
    // rows 0,130,131 full; rows 1..129 cols {0,1,130,131,132}.
    for (int i = tid; i < 1432; i += TPB) {
        int r, c;
        if (i < 399) { r = (i < 133) ? 0 : (i < 266 ? 130 : 131);
                       c = i - ((i < 133) ? 0 : (i < 266 ? 133 : 266)); }
        else { int k = i - 399; r = 1 + (k >> 3);
               const int map[8] = {0, 1, 130, 131, 132, 0, 1, 130};
               c = map[k & 7]; }
        P[r * PITCH + c] = 0;
    }
    if (tid == 0) P[PLDS - 1] = 0;

    // Vertical-pair pack: P[pr*133+pc] = half2(pad[pr][pc], pad[pr+1][pc]),
    // pad = image with 2-cell zero ring. Only pc in [2,129] nonzero.
    const float4* src = (const float4*)(x + img * NI * NI);
    for (int i = tid; i < 129 * 32; i += TPB) {
        int pr  = 1 + (i >> 5);
        int g   = i & 31;
        int rlo = pr - 2;
        int rhi = pr - 1;
        float4 vlo = (rlo >= 0)   ? src[rlo * 32 + g] : make_float4(0, 0, 0, 0);
        float4 vhi = (rhi <= 127) ? src[rhi * 32 + g] : make_float4(0, 0, 0, 0);
        int base = pr * PITCH + 2 + g * 4;
        P[base + 0] = __builtin_bit_cast(unsigned int, __builtin_amdgcn_cvt_pkrtz(vlo.x, vhi.x));
        P[base + 1] = __builtin_bit_cast(unsigned int, __builtin_amdgcn_cvt_pkrtz(vlo.y, vhi.y));
        P[base + 2] = __builtin_bit_cast(unsigned int, __builtin_amdgcn_cvt_pkrtz(vlo.z, vhi.z));
        P[base + 3] = __builtin_bit_cast(unsigned int, __builtin_amdgcn_cvt_pkrtz(vlo.w, vhi.w));
    }
    __syncthreads();

    const int w_id = tid >> 6;
    const int lane = tid & 63;
    const int slot = blk * WAVES + w_id;      // 0..831

    const char* Pb = (const char*)P;
    const float inv_dx = 1.0f / DX_F;
    const float inv_dt = 1.0f / DT_F;
    const float t0v    = -RHO_F + 0.5f * DT_F;
    const float LIM    = 20.157f;   // bilinear support |p| <= 20 + DX/2 (+ fp margin)

    for (int r = 0; r < TROUNDS; ++r) {
        const int task = r * SLOTS + slot;    // wave-uniform
        if (task >= NTASKS) break;            // only possible at r==15
        const int ap = task / 92;             // 0..142 (142 = angle self-pair)
        const int j  = task - ap * 92;        // 0..91  (91  = det self-pair)

        const float ang = ((float)ap + 0.5f) * (PI_F / (float)NA);
        float sn, cs;
        sincosf(ang, &sn, &cs);
        const float s = -RHO_F + ((float)j + 0.5f) * (2.0f * RHO_F / (float)ND);

        const float e0 = -s * sn;
        const float e1 =  s * cs;
        const float c0p = (e0 + t0v * cs + 20.0f) * inv_dx + 1.5f;  // padded
        const float c1p = (e1 + t0v * sn + 20.0f) * inv_dx + 1.5f;
        const float st0 = DT_F * cs * inv_dx;
        const float st1 = DT_F * sn * inv_dx;

        // Clip to bilinear support.
        const float inv_cs = 1.0f / cs;
        const float inv_sn = 1.0f / sn;
        float ta = (-LIM - e0) * inv_cs, tb = (LIM - e0) * inv_cs;
        float tc = (-LIM - e1) * inv_sn, td = (LIM - e1) * inv_sn;
        float tlo = fmaxf(fminf(ta, tb), fminf(tc, td));
        float thi = fminf(fmaxf(ta, tb), fmaxf(tc, td));
        float fk0 = fminf(fmaxf(ceilf((tlo - t0v) * inv_dt), 0.0f), 384.0f);
        float fk1 = fminf(fmaxf(floorf((thi - t0v) * inv_dt), -1.0f), 383.0f);
        const int kmin  = (int)fk0;
        const int kmax  = (int)fk1;
        const int count = kmax - kmin + 1;
        const int ntile = (count > 0) ? ((count + 63) >> 6) : 0;

        // Lane k = kmin + lane + 64*m; overrun past kmax clamps to zero
        // rows/cols (same mechanism as before) -> contributes exactly 0.
        float i0 = fmaf((float)(kmin + lane), st0, c0p);
        float i1 = fmaf((float)(kmin + lane), st1, c1p);
        const float st0s = st0 * 64.0f;
        const float st1s = st1 * 64.0f;
        float acc0 = 0.0f, acc1 = 0.0f, acc2 = 0.0f, acc3 = 0.0f;

        #pragma unroll 2
        for (int m = 0; m < ntile; ++m) {
            // Clamp [0.5,130.49] via med3: identity in-support; overrun ->
            // zero rows/cols for all 4 symmetric reads.
            float q0 = __builtin_amdgcn_fmed3f(i0, 0.5f, 130.49f);
            float q1 = __builtin_amdgcn_fmed3f(i1, 0.5f, 130.49f);
            i0 += st0s;
            i1 += st1s;
            float f0 = floorf(q0);
            float f1 = floorf(q1);
            float a0 = q0 - f0;
            float a1 = q1 - f1;
            // Byte offsets, float-domain (exact: max 130*532+520 < 2^24).
            float f1b = 4.0f * f1;
            int bidx  = (int)fmaf(f0, 532.0f, f1b);
            int bidx1 = BIDXM - bidx;
            int bidx2 = (int)fmaf(f0, 532.0f, 520.0f - f1b);
            int bidx3 = BIDXM - bidx2;
            unsigned int u0 = *(const unsigned int*)(Pb + bidx);
            unsigned int u1 = *(const unsigned int*)(Pb + bidx + 4);
            unsigned int m0 = *(const unsigned int*)(Pb + bidx1);
            unsigned int m1 = *(const unsigned int*)(Pb + bidx1 + 4);
            unsigned int r0 = *(const unsigned int*)(Pb + bidx2);
            unsigned int r1 = *(const unsigned int*)(Pb + bidx2 + 4);
            unsigned int s0 = *(const unsigned int*)(Pb + bidx3);
            unsigned int s1 = *(const unsigned int*)(Pb + bidx3 + 4);
            half2v w  = __builtin_amdgcn_cvt_pkrtz(1.0f - a0, a0);
            half2v b1 = __builtin_amdgcn_cvt_pkrtz(a1, a1);
            half2v wB = w * b1;                       // v_pk_mul_f16
            half2v wA = w - wB;                       // v_pk_add_f16 (== w*(1-a1))
            unsigned int wAu = __builtin_bit_cast(unsigned int, wA);
            unsigned int wBu = __builtin_bit_cast(unsigned int, wB);
            half2v wmA = __builtin_bit_cast(half2v, __builtin_amdgcn_alignbit(wAu, wAu, 16));
            half2v wmB = __builtin_bit_cast(half2v, __builtin_amdgcn_alignbit(wBu, wBu, 16));
            acc0 = __builtin_amdgcn_fdot2(__builtin_bit_cast(half2v, u0), wA, acc0, false);
            acc0 = __builtin_amdgcn_fdot2(__builtin_bit_cast(half2v, u1), wB, acc0, false);
            acc1 = __builtin_amdgcn_fdot2(__builtin_bit_cast(half2v, m0), wmB, acc1, false);
            acc1 = __builtin_amdgcn_fdot2(__builtin_bit_cast(half2v, m1), wmA, acc1, false);
            acc2 = __builtin_amdgcn_fdot2(__builtin_bit_cast(half2v, r0), wB, acc2, false);
            acc2 = __builtin_amdgcn_fdot2(__builtin_bit_cast(half2v, r1), wA, acc2, false);
            acc3 = __builtin_amdgcn_fdot2(__builtin_bit_cast(half2v, s0), wmA, acc3, false);
            acc3 = __builtin_amdgcn_fdot2(__builtin_bit_cast(half2v, s1), wmB, acc3, false);
        }

        // Reduce the 4 accs across 64 lanes -> lanes 0..3 hold acc0..3.
        // Stage 1 (xor 1): even lanes gather acc0/acc2 pairs, odd acc1/acc3.
        const bool o1 = lane & 1;
        float c01 = o1 ? acc1 : acc0;
        float t1a = o1 ? acc0 : acc1;
        c01 += __shfl_xor(t1a, 1, 64);
        float c23 = o1 ? acc3 : acc2;
        float t1b = o1 ? acc2 : acc3;
        c23 += __shfl_xor(t1b, 1, 64);
        // Stage 2 (xor 2): lane%4==q now holds acc_q over its 4-lane quad.
        const bool o2 = lane & 2;
        float d  = o2 ? c23 : c01;
        float t2 = o2 ? c01 : c23;
        d += __shfl_xor(t2, 2, 64);
        // Butterfly the 16 quads.
        d += __shfl_xor(d, 4, 64);
        d += __shfl_xor(d, 8, 64);
        d += __shfl_xor(d, 16, 64);
        d += __shfl_xor(d, 32, 64);

        if (lane < 4) {
            const int q   = lane;
            const int ao  = (q & 2) ? (284 - ap) : ap;
            const int det = (q & 1) ? (182 - j) : j;
            // ap==142 / j==91 self-pairs: double-writes are fp-equal
            // (commuted-add tree shapes) — benign.
            out[img * RAYS + ao * ND + det] = d * (DT_F / 12.0f);
        }
    }
}

extern "C" void kernel_launch(void* const* d_in, const int* in_sizes, int n_in,
                              void* d_out, int out_size, void* d_ws, size_t ws_size,
                              hipStream_t stream) {
    const float* x = (const float*)d_in[0];
    float* out = (float*)d_out;
    const int B = in_sizes[0] / (NI * NI);   // 8
    dim3 grid(B * 64);
    radon_fwd<<<grid, TPB, 0, stream>>>(x, out);
}

// Round 8
// 86.118 us; speedup vs baseline: 1.2976x; 1.2976x over previous
//
#include <hip/hip_runtime.h>
#include <stdint.h>

#define NI 128
#define NA 285
#define ND 183
#define NT 384
#define RAYS (NA * ND)        // 52155
#define PITCH 133             // dwords per packed row
#define PROWS 132
#define PLDS (PROWS * PITCH + 1)  // 17557 dwords = 70,228 B -> 2 blocks/CU
#define TPB 832               // 13 waves; grid 64 blocks/img
#define WAVES 13
#define SLOTS 832             // wave slots per image
#define NCH 36                // ceil(143/4) chunks of 4 angle-pairs
#define NTASKS (92 * NCH)     // 3312 wave-tasks per image
#define TROUNDS 4             // ceil(3312/832)
#define IDXM 17420            // 130*133+130: det-mirror idx' = IDXM - idx
#define BIDXM (IDXM * 4)      // byte-domain mirror constant

typedef __fp16 half2v __attribute__((ext_vector_type(2)));

constexpr float PI_F  = 3.14159265358979323846f;
constexpr float RHO_F = 28.284271247461902f;   // 20*sqrt(2)
constexpr float DX_F  = 0.3125f;
constexpr float DT_F  = 2.0f * RHO_F / NT;

// R21: R19 skeleton + progression-structured lanes.
// R20 proved progression addresses cut conflicts (6.53->4.45M) but its
// wave-per-group granularity (3.5 iters between ~700cyc serial task
// overheads x16 rounds) doubled the wall. Compose both lessons:
// wave = (j, 4 adjacent angle-pairs) x 16 lanes/angle; lane l walks
// samples k = kmin + l + 16m (consecutive within an instruction). Each
// ds_read2's 64 addrs = 4 floor-quantized arithmetic progressions
// (stride ~0.471*(133c-+s) dwords): bank load gcd-driven, <=2-way (free,
// m136) for most strides vs R19's 32 random progressions-of-2 (~6-8 max
// birthday load). 3312 tasks / 4 rounds: per-task overhead ~3%;
// 16-sample tile waste ~4% (< R19's parity+envelope ~10%); envelope over
// 4 adjacent angles (tighter than 16). Inner body verbatim R19.
// Out-of-chord / empty-chord / pad-angle lanes: positions fall outside
// the support -> fmed3 clamp lands on the zero ring -> contribute exact
// zeros (same mechanism as R19's overrun).
// Column 1 MUST stay zero (pad col 1 = image col -1): mirror reads at
// col' = 130-f1 hit it for in-support boundary samples (R13's bug).
__global__ __launch_bounds__(TPB) void radon_fwd(const float* __restrict__ x,
                                                 float* __restrict__ out) {
    __shared__ __align__(16) unsigned int P[PLDS];
    const int tid = threadIdx.x;
    const int img = blockIdx.x >> 6;
    const int blk = blockIdx.x & 63;

    // Ring-only zero fill (disjoint from pack writes -> single barrier).
    // rows 0,130,131 full; rows 1..129 cols {0,1,130,131,132}.
    for (int i = tid; i < 1432; i += TPB) {
        int r, c;
        if (i < 399) { r = (i < 133) ? 0 : (i < 266 ? 130 : 131);
                       c = i - ((i < 133) ? 0 : (i < 266 ? 133 : 266)); }
        else { int k = i - 399; r = 1 + (k >> 3);
               const int map[8] = {0, 1, 130, 131, 132, 0, 1, 130};
               c = map[k & 7]; }
        P[r * PITCH + c] = 0;
    }
    if (tid == 0) P[PLDS - 1] = 0;

    // Vertical-pair pack: P[pr*133+pc] = half2(pad[pr][pc], pad[pr+1][pc]),
    // pad = image with 2-cell zero ring. Only pc in [2,129] nonzero.
    const float4* src = (const float4*)(x + img * NI * NI);
    for (int i = tid; i < 129 * 32; i += TPB) {
        int pr  = 1 + (i >> 5);
        int g   = i & 31;
        int rlo = pr - 2;
        int rhi = pr - 1;
        float4 vlo = (rlo >= 0)   ? src[rlo * 32 + g] : make_float4(0, 0, 0, 0);
        float4 vhi = (rhi <= 127) ? src[rhi * 32 + g] : make_float4(0, 0, 0, 0);
        int base = pr * PITCH + 2 + g * 4;
        P[base + 0] = __builtin_bit_cast(unsigned int, __builtin_amdgcn_cvt_pkrtz(vlo.x, vhi.x));
        P[base + 1] = __builtin_bit_cast(unsigned int, __builtin_amdgcn_cvt_pkrtz(vlo.y, vhi.y));
        P[base + 2] = __builtin_bit_cast(unsigned int, __builtin_amdgcn_cvt_pkrtz(vlo.z, vhi.z));
        P[base + 3] = __builtin_bit_cast(unsigned int, __builtin_amdgcn_cvt_pkrtz(vlo.w, vhi.w));
    }
    __syncthreads();

    const int w_id = tid >> 6;
    const int lane = tid & 63;
    const int slot = blk * WAVES + w_id;      // 0..831
    const int gidx = lane >> 4;               // angle within chunk (0..3)
    const int l    = lane & 15;               // sample offset within group

    const char* Pb = (const char*)P;
    const float inv_dx = 1.0f / DX_F;
    const float inv_dt = 1.0f / DT_F;
    const float t0v    = -RHO_F + 0.5f * DT_F;
    const float LIM    = 20.157f;   // bilinear support |p| <= 20 + DX/2 (+ fp margin)

    for (int r = 0; r < TROUNDS; ++r) {
        const int task = r * SLOTS + slot;    // wave-uniform
        if (task >= NTASKS) break;            // only possible at r==3
        const int j  = task / NCH;            // det-pair index 0..91
        const int ch = task - j * NCH;        // angle chunk 0..35
        const int ap = ch * 4 + gidx;         // 0..143 (143 = pad)
        const bool apv = (ap < 143);

        const float ang = ((float)ap + 0.5f) * (PI_F / (float)NA);
        float sn, cs;
        sincosf(ang, &sn, &cs);
        const float s = -RHO_F + ((float)j + 0.5f) * (2.0f * RHO_F / (float)ND);

        const float e0 = -s * sn;
        const float e1 =  s * cs;
        const float c0p = (e0 + t0v * cs + 20.0f) * inv_dx + 1.5f;  // padded
        const float c1p = (e1 + t0v * sn + 20.0f) * inv_dx + 1.5f;
        const float st0 = DT_F * cs * inv_dx;
        const float st1 = DT_F * sn * inv_dx;

        // Clip to bilinear support.
        const float inv_cs = 1.0f / cs;
        const float inv_sn = 1.0f / sn;
        float ta = (-LIM - e0) * inv_cs, tb = (LIM - e0) * inv_cs;
        float tc = (-LIM - e1) * inv_sn, td = (LIM - e1) * inv_sn;
        float tlo = fmaxf(fminf(ta, tb), fminf(tc, td));
        float thi = fminf(fmaxf(ta, tb), fmaxf(tc, td));
        float fk0 = fminf(fmaxf(ceilf((tlo - t0v) * inv_dt), 0.0f), 384.0f);
        float fk1 = fminf(fmaxf(floorf((thi - t0v) * inv_dt), -1.0f), 383.0f);
        const int kmin  = (int)fk0;
        const int kmax  = (int)fk1;
        const int count = kmax - kmin + 1;
        int mylen = (apv && count > 0) ? ((count + 15) >> 4) : 0;

        // Wave envelope (4 adjacent angle-pairs at fixed j -> tight).
        int Lw = mylen;
        #pragma unroll
        for (int off = 32; off >= 1; off >>= 1)
            Lw = max(Lw, __shfl_xor(Lw, off, 64));

        // Lane l walks k = kmin + l + 16m; overrun/pad lanes clamp onto
        // the zero ring -> contribute exactly 0.
        float i0 = fmaf((float)(kmin + l), st0, c0p);
        float i1 = fmaf((float)(kmin + l), st1, c1p);
        const float st0s = st0 * 16.0f;
        const float st1s = st1 * 16.0f;
        float acc0 = 0.0f, acc1 = 0.0f, acc2 = 0.0f, acc3 = 0.0f;

        #pragma unroll 4
        for (int m = 0; m < Lw; ++m) {
            // Clamp [0.5,130.49] via med3: identity in-support; overrun ->
            // zero rows/cols for all 4 symmetric reads.
            float q0 = __builtin_amdgcn_fmed3f(i0, 0.5f, 130.49f);
            float q1 = __builtin_amdgcn_fmed3f(i1, 0.5f, 130.49f);
            i0 += st0s;
            i1 += st1s;
            float f0 = floorf(q0);
            float f1 = floorf(q1);
            float a0 = q0 - f0;
            float a1 = q1 - f1;
            // Byte offsets, float-domain (exact: max 130*532+520 < 2^24).
            float f1b = 4.0f * f1;
            int bidx  = (int)fmaf(f0, 532.0f, f1b);
            int bidx1 = BIDXM - bidx;
            int bidx2 = (int)fmaf(f0, 532.0f, 520.0f - f1b);
            int bidx3 = BIDXM - bidx2;
            unsigned int u0 = *(const unsigned int*)(Pb + bidx);
            unsigned int u1 = *(const unsigned int*)(Pb + bidx + 4);
            unsigned int m0 = *(const unsigned int*)(Pb + bidx1);
            unsigned int m1 = *(const unsigned int*)(Pb + bidx1 + 4);
            unsigned int r0 = *(const unsigned int*)(Pb + bidx2);
            unsigned int r1 = *(const unsigned int*)(Pb + bidx2 + 4);
            unsigned int s0 = *(const unsigned int*)(Pb + bidx3);
            unsigned int s1 = *(const unsigned int*)(Pb + bidx3 + 4);
            half2v w  = __builtin_amdgcn_cvt_pkrtz(1.0f - a0, a0);
            half2v b1 = __builtin_amdgcn_cvt_pkrtz(a1, a1);
            half2v wB = w * b1;                       // v_pk_mul_f16
            half2v wA = w - wB;                       // v_pk_add_f16 (== w*(1-a1))
            unsigned int wAu = __builtin_bit_cast(unsigned int, wA);
            unsigned int wBu = __builtin_bit_cast(unsigned int, wB);
            half2v wmA = __builtin_bit_cast(half2v, __builtin_amdgcn_alignbit(wAu, wAu, 16));
            half2v wmB = __builtin_bit_cast(half2v, __builtin_amdgcn_alignbit(wBu, wBu, 16));
            acc0 = __builtin_amdgcn_fdot2(__builtin_bit_cast(half2v, u0), wA, acc0, false);
            acc0 = __builtin_amdgcn_fdot2(__builtin_bit_cast(half2v, u1), wB, acc0, false);
            acc1 = __builtin_amdgcn_fdot2(__builtin_bit_cast(half2v, m0), wmB, acc1, false);
            acc1 = __builtin_amdgcn_fdot2(__builtin_bit_cast(half2v, m1), wmA, acc1, false);
            acc2 = __builtin_amdgcn_fdot2(__builtin_bit_cast(half2v, r0), wB, acc2, false);
            acc2 = __builtin_amdgcn_fdot2(__builtin_bit_cast(half2v, r1), wA, acc2, false);
            acc3 = __builtin_amdgcn_fdot2(__builtin_bit_cast(half2v, s0), wmA, acc3, false);
            acc3 = __builtin_amdgcn_fdot2(__builtin_bit_cast(half2v, s1), wmB, acc3, false);
        }

        // Reduce 4 accs over each 16-lane group (xor 1,2 interleave then
        // xor 4,8 butterflies -> every lane holds acc_{lane&3}).
        const bool o1 = lane & 1;
        float c01 = o1 ? acc1 : acc0;
        float t1a = o1 ? acc0 : acc1;
        c01 += __shfl_xor(t1a, 1, 64);
        float c23 = o1 ? acc3 : acc2;
        float t1b = o1 ? acc2 : acc3;
        c23 += __shfl_xor(t1b, 1, 64);
        const bool o2 = lane & 2;
        float d  = o2 ? c23 : c01;
        float t2 = o2 ? c01 : c23;
        d += __shfl_xor(t2, 2, 64);
        d += __shfl_xor(d, 4, 64);
        d += __shfl_xor(d, 8, 64);

        if (apv && (lane & 12) == 0) {
            const int q   = lane & 3;
            const int ao  = (q & 2) ? (284 - ap) : ap;
            const int det = (q & 1) ? (182 - j) : j;
            // ap==142 / j==91 self-pairs: same-address writes differ by
            // ~1 ulp (accumulation order) — benign at absmax 7.8e-3.
            out[img * RAYS + ao * ND + det] = d * (DT_F / 12.0f);
        }
    }
}

extern "C" void kernel_launch(void* const* d_in, const int* in_sizes, int n_in,
                              void* d_out, int out_size, void* d_ws, size_t ws_size,
                              hipStream_t stream) {
    const float* x = (const float*)d_in[0];
    float* out = (float*)d_out;
    const int B = in_sizes[0] / (NI * NI);   // 8
    dim3 grid(B * 64);
    radon_fwd<<<grid, TPB, 0, stream>>>(x, out);
}

// Round 9
// 82.071 us; speedup vs baseline: 1.3616x; 1.0493x over previous
//
#include <hip/hip_runtime.h>
#include <stdint.h>

#define NI 128
#define NA 285
#define ND 183
#define NT 384
#define RAYS (NA * ND)        // 52155
#define PITCH 133             // dwords per packed row
#define PROWS 132
#define PLDS (PROWS * PITCH + 1)  // 17557 dwords = 70,228 B -> 2 blocks/CU
#define TPB 1024              // 16 waves; 32 waves/CU = 8/SIMD (HW max)
#define WAVES 16
#define SLOTS 1024            // wave slots per image (64 blocks x 16)
#define NCH 36                // ceil(143/4) chunks of 4 angle-pairs
#define NTASKS (92 * NCH)     // 3312 wave-tasks per image
#define TROUNDS 4             // ceil(3312/1024); round 3 has 240 active
#define IDXM 17420            // 130*133+130: det-mirror idx' = IDXM - idx
#define BIDXM (IDXM * 4)      // byte-domain mirror constant

typedef __fp16 half2v __attribute__((ext_vector_type(2)));

constexpr float PI_F  = 3.14159265358979323846f;
constexpr float RHO_F = 28.284271247461902f;   // 20*sqrt(2)
constexpr float DX_F  = 0.3125f;
constexpr float DT_F  = 2.0f * RHO_F / NT;

// R22: R21 + full occupancy (TPB 832->1024: 26->32 waves/CU, 8/SIMD max).
// R21 post-mortem: conflicts 6.53M->2.41M (progression model CONFIRMED),
// dur 40.8us, but no pipe saturated (VALU ~45% true, DS ~22%, conflicts
// ~10%) -> residual is latency bubbles; occupancy stuck ~25% across
// R16-R21 with 13-wave blocks. Resource check: LDS 70,656x2 = 141KB <=
// 160KB; VGPR 36 <= 64 for 8 waves/SIMD. Round-3 tail (240 of 1024
// slots) scattered via odd-multiplier bijection perm = slot*409 mod 1024
// (else blocks 0-14 of each img would do 25% extra work); also spreads
// each slot's 4 tasks across the j-range (chord-length diversity ->
// balanced per-slot work). Inner body/lane geometry/reduce byte-identical
// to R21:
//  wave = (j, 4 adjacent angle-pairs) x 16 lanes/angle; lane l walks
//  k = kmin + l + 16m; each ds_read2 = 4 arithmetic progressions ->
//  near-conflict-free; 4-ray symmetry amortizes position/weight VALU.
// Out-of-chord / empty-chord / pad-angle lanes clamp onto the zero ring
// -> contribute exact zeros.
// Column 1 MUST stay zero (pad col 1 = image col -1): mirror reads at
// col' = 130-f1 hit it for in-support boundary samples (R13's bug).
__global__ __launch_bounds__(TPB) void radon_fwd(const float* __restrict__ x,
                                                 float* __restrict__ out) {
    __shared__ __align__(16) unsigned int P[PLDS];
    const int tid = threadIdx.x;
    const int img = blockIdx.x >> 6;
    const int blk = blockIdx.x & 63;

    // Ring-only zero fill (disjoint from pack writes -> single barrier).
    // rows 0,130,131 full; rows 1..129 cols {0,1,130,131,132}.
    for (int i = tid; i < 1432; i += TPB) {
        int r, c;
        if (i < 399) { r = (i < 133) ? 0 : (i < 266 ? 130 : 131);
                       c = i - ((i < 133) ? 0 : (i < 266 ? 133 : 266)); }
        else { int k = i - 399; r = 1 + (k >> 3);
               const int map[8] = {0, 1, 130, 131, 132, 0, 1, 130};
               c = map[k & 7]; }
        P[r * PITCH + c] = 0;
    }
    if (tid == 0) P[PLDS - 1] = 0;

    // Vertical-pair pack: P[pr*133+pc] = half2(pad[pr][pc], pad[pr+1][pc]),
    // pad = image with 2-cell zero ring. Only pc in [2,129] nonzero.
    const float4* src = (const float4*)(x + img * NI * NI);
    for (int i = tid; i < 129 * 32; i += TPB) {
        int pr  = 1 + (i >> 5);
        int g   = i & 31;
        int rlo = pr - 2;
        int rhi = pr - 1;
        float4 vlo = (rlo >= 0)   ? src[rlo * 32 + g] : make_float4(0, 0, 0, 0);
        float4 vhi = (rhi <= 127) ? src[rhi * 32 + g] : make_float4(0, 0, 0, 0);
        int base = pr * PITCH + 2 + g * 4;
        P[base + 0] = __builtin_bit_cast(unsigned int, __builtin_amdgcn_cvt_pkrtz(vlo.x, vhi.x));
        P[base + 1] = __builtin_bit_cast(unsigned int, __builtin_amdgcn_cvt_pkrtz(vlo.y, vhi.y));
        P[base + 2] = __builtin_bit_cast(unsigned int, __builtin_amdgcn_cvt_pkrtz(vlo.z, vhi.z));
        P[base + 3] = __builtin_bit_cast(unsigned int, __builtin_amdgcn_cvt_pkrtz(vlo.w, vhi.w));
    }
    __syncthreads();

    const int w_id = tid >> 6;
    const int lane = tid & 63;
    const int slot = blk * WAVES + w_id;        // 0..1023
    const int perm = (slot * 409) & 1023;       // odd mult -> bijection
    const int gidx = lane >> 4;                 // angle within chunk (0..3)
    const int l    = lane & 15;                 // sample offset within group

    const char* Pb = (const char*)P;
    const float inv_dx = 1.0f / DX_F;
    const float inv_dt = 1.0f / DT_F;
    const float t0v    = -RHO_F + 0.5f * DT_F;
    const float LIM    = 20.157f;   // bilinear support |p| <= 20 + DX/2 (+ fp margin)

    for (int r = 0; r < TROUNDS; ++r) {
        const int task = r * SLOTS + perm;    // wave-uniform
        if (task >= NTASKS) break;            // only possible at r==3
        const int j  = task / NCH;            // det-pair index 0..91
        const int ch = task - j * NCH;        // angle chunk 0..35
        const int ap = ch * 4 + gidx;         // 0..143 (143 = pad)
        const bool apv = (ap < 143);

        const float ang = ((float)ap + 0.5f) * (PI_F / (float)NA);
        float sn, cs;
        sincosf(ang, &sn, &cs);
        const float s = -RHO_F + ((float)j + 0.5f) * (2.0f * RHO_F / (float)ND);

        const float e0 = -s * sn;
        const float e1 =  s * cs;
        const float c0p = (e0 + t0v * cs + 20.0f) * inv_dx + 1.5f;  // padded
        const float c1p = (e1 + t0v * sn + 20.0f) * inv_dx + 1.5f;
        const float st0 = DT_F * cs * inv_dx;
        const float st1 = DT_F * sn * inv_dx;

        // Clip to bilinear support.
        const float inv_cs = 1.0f / cs;
        const float inv_sn = 1.0f / sn;
        float ta = (-LIM - e0) * inv_cs, tb = (LIM - e0) * inv_cs;
        float tc = (-LIM - e1) * inv_sn, td = (LIM - e1) * inv_sn;
        float tlo = fmaxf(fminf(ta, tb), fminf(tc, td));
        float thi = fminf(fmaxf(ta, tb), fmaxf(tc, td));
        float fk0 = fminf(fmaxf(ceilf((tlo - t0v) * inv_dt), 0.0f), 384.0f);
        float fk1 = fminf(fmaxf(floorf((thi - t0v) * inv_dt), -1.0f), 383.0f);
        const int kmin  = (int)fk0;
        const int kmax  = (int)fk1;
        const int count = kmax - kmin + 1;
        int mylen = (apv && count > 0) ? ((count + 15) >> 4) : 0;

        // Wave envelope (4 adjacent angle-pairs at fixed j -> tight).
        int Lw = mylen;
        #pragma unroll
        for (int off = 32; off >= 1; off >>= 1)
            Lw = max(Lw, __shfl_xor(Lw, off, 64));

        // Lane l walks k = kmin + l + 16m; overrun/pad lanes clamp onto
        // the zero ring -> contribute exactly 0.
        float i0 = fmaf((float)(kmin + l), st0, c0p);
        float i1 = fmaf((float)(kmin + l), st1, c1p);
        const float st0s = st0 * 16.0f;
        const float st1s = st1 * 16.0f;
        float acc0 = 0.0f, acc1 = 0.0f, acc2 = 0.0f, acc3 = 0.0f;

        #pragma unroll 4
        for (int m = 0; m < Lw; ++m) {
            // Clamp [0.5,130.49] via med3: identity in-support; overrun ->
            // zero rows/cols for all 4 symmetric reads.
            float q0 = __builtin_amdgcn_fmed3f(i0, 0.5f, 130.49f);
            float q1 = __builtin_amdgcn_fmed3f(i1, 0.5f, 130.49f);
            i0 += st0s;
            i1 += st1s;
            float f0 = floorf(q0);
            float f1 = floorf(q1);
            float a0 = q0 - f0;
            float a1 = q1 - f1;
            // Byte offsets, float-domain (exact: max 130*532+520 < 2^24).
            float f1b = 4.0f * f1;
            int bidx  = (int)fmaf(f0, 532.0f, f1b);
            int bidx1 = BIDXM - bidx;
            int bidx2 = (int)fmaf(f0, 532.0f, 520.0f - f1b);
            int bidx3 = BIDXM - bidx2;
            unsigned int u0 = *(const unsigned int*)(Pb + bidx);
            unsigned int u1 = *(const unsigned int*)(Pb + bidx + 4);
            unsigned int m0 = *(const unsigned int*)(Pb + bidx1);
            unsigned int m1 = *(const unsigned int*)(Pb + bidx1 + 4);
            unsigned int r0 = *(const unsigned int*)(Pb + bidx2);
            unsigned int r1 = *(const unsigned int*)(Pb + bidx2 + 4);
            unsigned int s0 = *(const unsigned int*)(Pb + bidx3);
            unsigned int s1 = *(const unsigned int*)(Pb + bidx3 + 4);
            half2v w  = __builtin_amdgcn_cvt_pkrtz(1.0f - a0, a0);
            half2v b1 = __builtin_amdgcn_cvt_pkrtz(a1, a1);
            half2v wB = w * b1;                       // v_pk_mul_f16
            half2v wA = w - wB;                       // v_pk_add_f16 (== w*(1-a1))
            unsigned int wAu = __builtin_bit_cast(unsigned int, wA);
            unsigned int wBu = __builtin_bit_cast(unsigned int, wB);
            half2v wmA = __builtin_bit_cast(half2v, __builtin_amdgcn_alignbit(wAu, wAu, 16));
            half2v wmB = __builtin_bit_cast(half2v, __builtin_amdgcn_alignbit(wBu, wBu, 16));
            acc0 = __builtin_amdgcn_fdot2(__builtin_bit_cast(half2v, u0), wA, acc0, false);
            acc0 = __builtin_amdgcn_fdot2(__builtin_bit_cast(half2v, u1), wB, acc0, false);
            acc1 = __builtin_amdgcn_fdot2(__builtin_bit_cast(half2v, m0), wmB, acc1, false);
            acc1 = __builtin_amdgcn_fdot2(__builtin_bit_cast(half2v, m1), wmA, acc1, false);
            acc2 = __builtin_amdgcn_fdot2(__builtin_bit_cast(half2v, r0), wB, acc2, false);
            acc2 = __builtin_amdgcn_fdot2(__builtin_bit_cast(half2v, r1), wA, acc2, false);
            acc3 = __builtin_amdgcn_fdot2(__builtin_bit_cast(half2v, s0), wmA, acc3, false);
            acc3 = __builtin_amdgcn_fdot2(__builtin_bit_cast(half2v, s1), wmB, acc3, false);
        }

        // Reduce 4 accs over each 16-lane group (xor 1,2 interleave then
        // xor 4,8 butterflies -> every lane holds acc_{lane&3}).
        const bool o1 = lane & 1;
        float c01 = o1 ? acc1 : acc0;
        float t1a = o1 ? acc0 : acc1;
        c01 += __shfl_xor(t1a, 1, 64);
        float c23 = o1 ? acc3 : acc2;
        float t1b = o1 ? acc2 : acc3;
        c23 += __shfl_xor(t1b, 1, 64);
        const bool o2 = lane & 2;
        float d  = o2 ? c23 : c01;
        float t2 = o2 ? c01 : c23;
        d += __shfl_xor(t2, 2, 64);
        d += __shfl_xor(d, 4, 64);
        d += __shfl_xor(d, 8, 64);

        if (apv && (lane & 12) == 0) {
            const int q   = lane & 3;
            const int ao  = (q & 2) ? (284 - ap) : ap;
            const int det = (q & 1) ? (182 - j) : j;
            // ap==142 / j==91 self-pairs: same-address writes differ by
            // ~1 ulp (accumulation order) — benign at absmax 7.8e-3.
            out[img * RAYS + ao * ND + det] = d * (DT_F / 12.0f);
        }
    }
}

extern "C" void kernel_launch(void* const* d_in, const int* in_sizes, int n_in,
                              void* d_out, int out_size, void* d_ws, size_t ws_size,
                              hipStream_t stream) {
    const float* x = (const float*)d_in[0];
    float* out = (float*)d_out;
    const int B = in_sizes[0] / (NI * NI);   // 8
    dim3 grid(B * 64);
    radon_fwd<<<grid, TPB, 0, stream>>>(x, out);
}